// Round 1
// baseline (141.000 us; speedup 1.0000x reference)
//
#include <hip/hip_runtime.h>
#include <hip/hip_bf16.h>
#include <stdint.h>

typedef unsigned short u16;
typedef __attribute__((ext_vector_type(8))) short bf16x8;   // 8 bf16 = 4 VGPR (MFMA A/B frag)
typedef __attribute__((ext_vector_type(4))) float f32x4;
typedef __attribute__((ext_vector_type(16))) float f32x16;

// ---------- helpers ----------
__device__ __forceinline__ u16 f2bf(float f) {          // RNE f32 -> bf16 (finite inputs)
  union { float f; uint32_t u; } a; a.f = f;
  return (u16)((a.u + 0x7FFFu + ((a.u >> 16) & 1u)) >> 16);
}

__device__ __forceinline__ void gload_lds16(const void* g, void* l) {
  // direct global->LDS, 16B per lane; LDS dest = wave-uniform base + lane*16
  auto* gp = (__attribute__((address_space(1))) void*)(uintptr_t)g;
  auto* lp = (__attribute__((address_space(3))) void*)(uintptr_t)l;
  __builtin_amdgcn_global_load_lds(gp, lp, 16, 0, 0);
}

// ---------- 0: f32 -> bf16 conversion / concat ----------
__global__ void cvt_kernel(const float4* __restrict__ x, const float4* __restrict__ wq,
                           const float4* __restrict__ wk, const float4* __restrict__ wv,
                           const float4* __restrict__ wo,
                           ushort4* __restrict__ xb, ushort4* __restrict__ wqkv,
                           ushort4* __restrict__ wob) {
  const int XN = (2 * 2048 * 1024) / 4;   // 1048576
  const int WN = (1024 * 1024) / 4;       // 262144  (2^18)
  const int total = XN + 4 * WN;
  for (int i = blockIdx.x * 256 + threadIdx.x; i < total; i += gridDim.x * 256) {
    float4 v; ushort4* dst;
    if (i < XN) { v = x[i]; dst = xb + i; }
    else {
      int j = i - XN; int m = j >> 18; int o = j & (WN - 1);
      const float4* src = (m == 0) ? wq : (m == 1) ? wk : (m == 2) ? wv : wo;
      v = src[o];
      dst = (m < 3) ? (wqkv + j) : (wob + o);
    }
    ushort4 r; r.x = f2bf(v.x); r.y = f2bf(v.y); r.z = f2bf(v.z); r.w = f2bf(v.w);
    *dst = r;
  }
}

// ---------- 1: lengths from prefix padding mask ----------
__global__ void len_kernel(const int* __restrict__ mask, int* __restrict__ lens) {
  __shared__ int red[256];
  int b = blockIdx.x, s = 0;
  for (int i = threadIdx.x; i < 2048; i += 256) s += mask[b * 2048 + i];
  red[threadIdx.x] = s;
  __syncthreads();
  if (threadIdx.x < 64) {
    int v = red[threadIdx.x] + red[threadIdx.x + 64] + red[threadIdx.x + 128] + red[threadIdx.x + 192];
    #pragma unroll
    for (int o = 32; o > 0; o >>= 1) v += __shfl_down(v, o);
    if (threadIdx.x == 0) lens[b] = v;
  }
}

// ---------- 2/4: BT GEMM  out[m][n] = sum_k A[m][k]*B[n][k]  (K=1024) ----------
// MODE 0: plain f32 store to outf[M][N]
// MODE 1: RoPE + scatter epilogue (N=3072 -> Q,K roped; V plain; Q scaled 1/32)
template <int MODE>
__global__ __launch_bounds__(256, 2)
void gemm_bt(const u16* __restrict__ A, const u16* __restrict__ Bm,
             int M, int N, float* __restrict__ outf,
             u16* __restrict__ Qb, u16* __restrict__ Kb, u16* __restrict__ VbT,
             const float* __restrict__ cosT, const float* __restrict__ sinT) {
  const int K = 1024;
  __shared__ alignas(16) u16 Alds[128 * 32];
  __shared__ alignas(16) u16 Blds[128 * 32];
  const int tid = threadIdx.x, lane = tid & 63, wid = tid >> 6;
  const int nTm = M >> 7;
  const int m0 = (blockIdx.x % nTm) << 7;
  const int n0 = (blockIdx.x / nTm) << 7;
  const int wm = (wid >> 1) << 6, wn = (wid & 1) << 6;
  const int lr = lane & 15, lg = lane >> 4;

  f32x4 acc[4][4];
  #pragma unroll
  for (int i = 0; i < 4; ++i)
    #pragma unroll
    for (int j = 0; j < 4; ++j)
      #pragma unroll
      for (int e = 0; e < 4; ++e) acc[i][j][e] = 0.0f;

  const int r4 = tid >> 2, c4 = (tid & 3) * 8;
  const u16* ag0 = A + (int64_t)(m0 + r4) * K + c4;
  const u16* ag1 = A + (int64_t)(m0 + 64 + r4) * K + c4;
  const u16* bg0 = Bm + (int64_t)(n0 + r4) * K + c4;
  const u16* bg1 = Bm + (int64_t)(n0 + 64 + r4) * K + c4;
  u16* al0 = &Alds[(tid & 192) * 8];
  u16* al1 = &Alds[(256 + (tid & 192)) * 8];
  u16* bl0 = &Blds[(tid & 192) * 8];
  u16* bl1 = &Blds[(256 + (tid & 192)) * 8];

  for (int kt = 0; kt < K / 32; ++kt) {
    const int ko = kt * 32;
    gload_lds16(ag0 + ko, al0);
    gload_lds16(ag1 + ko, al1);
    gload_lds16(bg0 + ko, bl0);
    gload_lds16(bg1 + ko, bl1);
    __syncthreads();
    bf16x8 af[4], bfm[4];
    #pragma unroll
    for (int i = 0; i < 4; ++i) af[i] = *(const bf16x8*)&Alds[(wm + i * 16 + lr) * 32 + lg * 8];
    #pragma unroll
    for (int i = 0; i < 4; ++i) bfm[i] = *(const bf16x8*)&Blds[(wn + i * 16 + lr) * 32 + lg * 8];
    #pragma unroll
    for (int mi = 0; mi < 4; ++mi)
      #pragma unroll
      for (int ni = 0; ni < 4; ++ni)
        acc[mi][ni] = __builtin_amdgcn_mfma_f32_16x16x32_bf16(af[mi], bfm[ni], acc[mi][ni], 0, 0, 0);
    __syncthreads();
  }

  if (MODE == 0) {
    #pragma unroll
    for (int mi = 0; mi < 4; ++mi)
      #pragma unroll
      for (int r = 0; r < 4; ++r) {
        const int row = m0 + wm + mi * 16 + lg * 4 + r;
        float* orow = outf + (int64_t)row * N + n0 + wn + lr;
        #pragma unroll
        for (int ni = 0; ni < 4; ++ni) orow[ni * 16] = acc[mi][ni][r];
      }
  } else {
    #pragma unroll
    for (int mi = 0; mi < 4; ++mi) {
      #pragma unroll
      for (int r = 0; r < 4; ++r) {
        const int row = m0 + wm + mi * 16 + lg * 4 + r;
        const int bb = row >> 11, ss = row & 2047;
        #pragma unroll
        for (int ni = 0; ni < 4; ++ni) {
          const int n = n0 + wn + ni * 16 + lr;
          float v = acc[mi][ni][r];
          if (n < 2048) {                       // Q or K: RoPE (wave-uniform branch)
            float partner = __shfl_xor(v, 1);
            const int ii = (n >> 1) & 31;
            const float c = cosT[ss * 32 + ii];
            const float sn = sinT[ss * 32 + ii];
            float rv = (n & 1) ? (partner * sn + v * c) : (v * c - partner * sn);
            const int h = (n >> 6) & 15, d = n & 63;
            const int idx = ((bb * 16 + h) * 2048 + ss) * 64 + d;
            if (n < 1024) Qb[idx] = f2bf(rv * 0.03125f);   // fold 1/sqrt(D)=1/32 into Q
            else          Kb[idx] = f2bf(rv);
          } else {                              // V: store transposed [bh][d][s]
            const int n2 = n - 2048;
            const int h = n2 >> 6, d = n2 & 63;
            VbT[((int64_t)(bb * 16 + h) * 64 + d) * 2048 + ss] = f2bf(v);
          }
        }
      }
    }
  }
}

// ---------- 3: flash attention ----------
// grid: 512 = 32 (b*h) * 16 qblocks; block: 4 waves, each owns 32 q-rows.
// swapped QK^T: S^T = mfma32x32x16(Kfrag, Qfrag) -> lane owns query q=lane&31,
// 16 keys in-lane + 16 in lane^32. O kept as O^T via mfma(V^T, P).
__global__ __launch_bounds__(256, 2)
void attn_kernel(const u16* __restrict__ Qb, const u16* __restrict__ Kb,
                 const u16* __restrict__ VbT, u16* __restrict__ attnb,
                 const int* __restrict__ lens) {
  __shared__ alignas(16) u16 Klds[2][32 * 64];   // [key][d], chunk-swizzled
  __shared__ alignas(16) u16 Vlds[2][64 * 32];   // [d][key], chunk-swizzled
  __shared__ alignas(16) u16 Plds[4][32 * 40];   // per-wave P[q][key], padded
  const int tid = threadIdx.x, lane = tid & 63, wid = tid >> 6;
  const int hi = lane >> 5, ql = lane & 31;
  const int bh = blockIdx.x >> 4;
  const int len = lens[bh >> 4];
  const int qrow = (blockIdx.x & 15) * 128 + wid * 32 + ql;

  // Q fragments (loop-invariant): B-operand, d-chunk c: d = c*16 + hi*8 + j
  bf16x8 qf[4];
  const u16* qptr = Qb + ((int64_t)bh * 2048 + qrow) * 64 + hi * 8;
  #pragma unroll
  for (int c = 0; c < 4; ++c) qf[c] = *(const bf16x8*)(qptr + c * 16);

  // staging source addresses (pre-swizzled so linear LDS holds swizzled layout)
  const int kkey = tid >> 3, kccs = (tid & 7) ^ (kkey & 7);
  const u16* kg = Kb + ((int64_t)bh * 2048 + kkey) * 64 + kccs * 8;
  const int vd = tid >> 2, vccs = (tid & 3) ^ (vd & 3);
  const u16* vg = VbT + ((int64_t)bh * 64 + vd) * 2048 + vccs * 8;
  const int wbase = (tid & 192) * 8;

  f32x16 oacc[2];
  #pragma unroll
  for (int r = 0; r < 16; ++r) { oacc[0][r] = 0.0f; oacc[1][r] = 0.0f; }
  float mrun = -1e30f, lrun = 0.0f;

  const int nt = (len + 31) >> 5;
  gload_lds16(kg, &Klds[0][wbase]);
  gload_lds16(vg, &Vlds[0][wbase]);
  __syncthreads();

  for (int t = 0; t < nt; ++t) {
    const int bu = t & 1;
    if (t + 1 < nt) {                       // prefetch next tile into other buffer
      const int k0n = (t + 1) * 32;
      gload_lds16(kg + (int64_t)k0n * 64, &Klds[bu ^ 1][wbase]);
      gload_lds16(vg + k0n, &Vlds[bu ^ 1][wbase]);
    }
    // QK^T (S^T): A = K tile, B = Q frags
    f32x16 sacc;
    #pragma unroll
    for (int r = 0; r < 16; ++r) sacc[r] = 0.0f;
    #pragma unroll
    for (int c = 0; c < 4; ++c) {
      const int cc = 2 * c + hi;
      bf16x8 kf = *(const bf16x8*)&Klds[bu][ql * 64 + ((cc ^ (ql & 7)) * 8)];
      sacc = __builtin_amdgcn_mfma_f32_32x32x16_bf16(kf, qf[c], sacc, 0, 0, 0);
    }
    const int k0 = t * 32;
    if (k0 + 32 > len) {                    // mask padded keys (last tile only)
      #pragma unroll
      for (int r = 0; r < 16; ++r) {
        const int key = k0 + (r & 3) + 8 * (r >> 2) + 4 * hi;
        if (key >= len) sacc[r] = -1e30f;
      }
    }
    // online softmax: lane owns query ql; partner lane^32 holds other 16 keys
    float pmax = sacc[0];
    #pragma unroll
    for (int r = 1; r < 16; ++r) pmax = fmaxf(pmax, sacc[r]);
    pmax = fmaxf(pmax, __shfl_xor(pmax, 32));
    const float mnew = fmaxf(mrun, pmax);
    const float scale = __expf(mrun - mnew);
    float p[16], psum = 0.0f;
    #pragma unroll
    for (int r = 0; r < 16; ++r) { p[r] = __expf(sacc[r] - mnew); psum += p[r]; }
    psum += __shfl_xor(psum, 32);
    lrun = lrun * scale + psum;
    mrun = mnew;
    #pragma unroll
    for (int r = 0; r < 16; ++r) { oacc[0][r] *= scale; oacc[1][r] *= scale; }
    // P (bf16) -> per-wave LDS, P[q][key]
    #pragma unroll
    for (int g = 0; g < 4; ++g) {
      ushort4 w;
      w.x = f2bf(p[4 * g + 0]); w.y = f2bf(p[4 * g + 1]);
      w.z = f2bf(p[4 * g + 2]); w.w = f2bf(p[4 * g + 3]);
      *(ushort4*)&Plds[wid][ql * 40 + 8 * g + 4 * hi] = w;
    }
    // PV: O^T += V^T * P   (A = V^T tile, B = P)
    #pragma unroll
    for (int dc = 0; dc < 2; ++dc)
      #pragma unroll
      for (int ks = 0; ks < 2; ++ks) {
        const int cc = 2 * ks + hi;
        const int d = dc * 32 + ql;
        bf16x8 vf = *(const bf16x8*)&Vlds[bu][d * 32 + ((cc ^ (d & 3)) * 8)];
        bf16x8 pf = *(const bf16x8*)&Plds[wid][ql * 40 + ks * 16 + 8 * hi];
        oacc[dc] = __builtin_amdgcn_mfma_f32_32x32x16_bf16(vf, pf, oacc[dc], 0, 0, 0);
      }
    __syncthreads();
  }

  // epilogue: normalize, write attn[row][h*64+d] as bf16
  const float inv = 1.0f / lrun;
  u16* outp = attnb + ((int64_t)((bh >> 4) * 2048 + qrow)) * 1024 + (bh & 15) * 64;
  #pragma unroll
  for (int dc = 0; dc < 2; ++dc)
    #pragma unroll
    for (int g = 0; g < 4; ++g) {
      ushort4 w;
      w.x = f2bf(oacc[dc][4 * g + 0] * inv);
      w.y = f2bf(oacc[dc][4 * g + 1] * inv);
      w.z = f2bf(oacc[dc][4 * g + 2] * inv);
      w.w = f2bf(oacc[dc][4 * g + 3] * inv);
      *(ushort4*)(outp + dc * 32 + 8 * g + 4 * hi) = w;
    }
}

// ---------- launch ----------
extern "C" void kernel_launch(void* const* d_in, const int* in_sizes, int n_in,
                              void* d_out, int out_size, void* d_ws, size_t ws_size,
                              hipStream_t stream) {
  const float* x    = (const float*)d_in[0];
  const float* wq   = (const float*)d_in[1];
  const float* wk   = (const float*)d_in[2];
  const float* wv   = (const float*)d_in[3];
  const float* wo   = (const float*)d_in[4];
  const float* fcos = (const float*)d_in[5];
  const float* fsin = (const float*)d_in[6];
  const int*   pmsk = (const int*)d_in[7];
  float* out = (float*)d_out;

  char* ws = (char*)d_ws;
  u16* XB    = (u16*)(ws);                          // 8 MB
  u16* WQKV  = (u16*)(ws + (size_t)8  * 1048576);   // 6 MB
  u16* WOB   = (u16*)(ws + (size_t)14 * 1048576);   // 2 MB
  u16* QB    = (u16*)(ws + (size_t)16 * 1048576);   // 8 MB
  u16* KB    = (u16*)(ws + (size_t)24 * 1048576);   // 8 MB
  u16* VBT   = (u16*)(ws + (size_t)32 * 1048576);   // 8 MB
  u16* ATTNB = (u16*)(ws + (size_t)40 * 1048576);   // 8 MB
  int* LENS  = (int*)(ws + (size_t)48 * 1048576);

  cvt_kernel<<<2048, 256, 0, stream>>>((const float4*)x, (const float4*)wq,
                                       (const float4*)wk, (const float4*)wv,
                                       (const float4*)wo, (ushort4*)XB,
                                       (ushort4*)WQKV, (ushort4*)WOB);
  len_kernel<<<2, 256, 0, stream>>>(pmsk, LENS);
  gemm_bt<1><<<768, 256, 0, stream>>>(XB, WQKV, 4096, 3072, nullptr,
                                      QB, KB, VBT, fcos, fsin);
  attn_kernel<<<512, 256, 0, stream>>>(QB, KB, VBT, ATTNB, LENS);
  gemm_bt<0><<<256, 256, 0, stream>>>(ATTNB, WOB, 4096, 1024, out,
                                      nullptr, nullptr, nullptr, nullptr, nullptr);
}

// Round 2
// 122.454 us; speedup vs baseline: 1.1515x; 1.1515x over previous
//
#include <hip/hip_runtime.h>
#include <hip/hip_bf16.h>
#include <stdint.h>

typedef unsigned short u16;
typedef __attribute__((ext_vector_type(8))) short bf16x8;   // 8 bf16 = 4 VGPR (MFMA A/B frag)
typedef __attribute__((ext_vector_type(4))) float f32x4;
typedef __attribute__((ext_vector_type(16))) float f32x16;

// ---------- helpers ----------
__device__ __forceinline__ u16 f2bf(float f) {          // RNE f32 -> bf16 (finite inputs)
  union { float f; uint32_t u; } a; a.f = f;
  return (u16)((a.u + 0x7FFFu + ((a.u >> 16) & 1u)) >> 16);
}

__device__ __forceinline__ void gload_lds16(const void* g, void* l) {
  // direct global->LDS, 16B per lane; LDS dest = wave-uniform base + lane*16
  auto* gp = (__attribute__((address_space(1))) void*)(uintptr_t)g;
  auto* lp = (__attribute__((address_space(3))) void*)(uintptr_t)l;
  __builtin_amdgcn_global_load_lds(gp, lp, 16, 0, 0);
}

__device__ __forceinline__ float exp2_fast(float x) {
  float r;
  asm("v_exp_f32 %0, %1" : "=v"(r) : "v"(x));
  return r;
}

#define CVTPK(d, a, b) asm("v_cvt_pk_bf16_f32 %0, %1, %2" : "=v"(d) : "v"(a), "v"(b))
#define SWAP32(a, b)   asm("v_permlane32_swap_b32 %0, %1" : "+v"(a), "+v"(b))

// ---------- 0: f32 -> bf16 conversion / concat ----------
__global__ void cvt_kernel(const float4* __restrict__ x, const float4* __restrict__ wq,
                           const float4* __restrict__ wk, const float4* __restrict__ wv,
                           const float4* __restrict__ wo,
                           ushort4* __restrict__ xb, ushort4* __restrict__ wqkv,
                           ushort4* __restrict__ wob) {
  const int XN = (2 * 2048 * 1024) / 4;   // 1048576
  const int WN = (1024 * 1024) / 4;       // 262144  (2^18)
  const int total = XN + 4 * WN;
  for (int i = blockIdx.x * 256 + threadIdx.x; i < total; i += gridDim.x * 256) {
    float4 v; ushort4* dst;
    if (i < XN) { v = x[i]; dst = xb + i; }
    else {
      int j = i - XN; int m = j >> 18; int o = j & (WN - 1);
      const float4* src = (m == 0) ? wq : (m == 1) ? wk : (m == 2) ? wv : wo;
      v = src[o];
      dst = (m < 3) ? (wqkv + j) : (wob + o);
    }
    ushort4 r; r.x = f2bf(v.x); r.y = f2bf(v.y); r.z = f2bf(v.z); r.w = f2bf(v.w);
    *dst = r;
  }
}

// ---------- 1: lengths from prefix padding mask ----------
__global__ void len_kernel(const int* __restrict__ mask, int* __restrict__ lens) {
  __shared__ int red[256];
  int b = blockIdx.x, s = 0;
  for (int i = threadIdx.x; i < 2048; i += 256) s += mask[b * 2048 + i];
  red[threadIdx.x] = s;
  __syncthreads();
  if (threadIdx.x < 64) {
    int v = red[threadIdx.x] + red[threadIdx.x + 64] + red[threadIdx.x + 128] + red[threadIdx.x + 192];
    #pragma unroll
    for (int o = 32; o > 0; o >>= 1) v += __shfl_down(v, o);
    if (threadIdx.x == 0) lens[b] = v;
  }
}

// ---------- 2/4: BT GEMM  out[m][n] = sum_k A[m][k]*B[n][k]  (K=1024) ----------
template <int MODE>
__global__ __launch_bounds__(256, 2)
void gemm_bt(const u16* __restrict__ A, const u16* __restrict__ Bm,
             int M, int N, float* __restrict__ outf,
             u16* __restrict__ Qb, u16* __restrict__ Kb, u16* __restrict__ VbT,
             const float* __restrict__ cosT, const float* __restrict__ sinT) {
  const int K = 1024;
  __shared__ alignas(16) u16 Alds[128 * 32];
  __shared__ alignas(16) u16 Blds[128 * 32];
  const int tid = threadIdx.x, lane = tid & 63, wid = tid >> 6;
  const int nTm = M >> 7;
  const int m0 = (blockIdx.x % nTm) << 7;
  const int n0 = (blockIdx.x / nTm) << 7;
  const int wm = (wid >> 1) << 6, wn = (wid & 1) << 6;
  const int lr = lane & 15, lg = lane >> 4;

  f32x4 acc[4][4];
  #pragma unroll
  for (int i = 0; i < 4; ++i)
    #pragma unroll
    for (int j = 0; j < 4; ++j)
      #pragma unroll
      for (int e = 0; e < 4; ++e) acc[i][j][e] = 0.0f;

  const int r4 = tid >> 2, c4 = (tid & 3) * 8;
  const u16* ag0 = A + (int64_t)(m0 + r4) * K + c4;
  const u16* ag1 = A + (int64_t)(m0 + 64 + r4) * K + c4;
  const u16* bg0 = Bm + (int64_t)(n0 + r4) * K + c4;
  const u16* bg1 = Bm + (int64_t)(n0 + 64 + r4) * K + c4;
  u16* al0 = &Alds[(tid & 192) * 8];
  u16* al1 = &Alds[(256 + (tid & 192)) * 8];
  u16* bl0 = &Blds[(tid & 192) * 8];
  u16* bl1 = &Blds[(256 + (tid & 192)) * 8];

  for (int kt = 0; kt < K / 32; ++kt) {
    const int ko = kt * 32;
    gload_lds16(ag0 + ko, al0);
    gload_lds16(ag1 + ko, al1);
    gload_lds16(bg0 + ko, bl0);
    gload_lds16(bg1 + ko, bl1);
    __syncthreads();
    bf16x8 af[4], bfm[4];
    #pragma unroll
    for (int i = 0; i < 4; ++i) af[i] = *(const bf16x8*)&Alds[(wm + i * 16 + lr) * 32 + lg * 8];
    #pragma unroll
    for (int i = 0; i < 4; ++i) bfm[i] = *(const bf16x8*)&Blds[(wn + i * 16 + lr) * 32 + lg * 8];
    #pragma unroll
    for (int mi = 0; mi < 4; ++mi)
      #pragma unroll
      for (int ni = 0; ni < 4; ++ni)
        acc[mi][ni] = __builtin_amdgcn_mfma_f32_16x16x32_bf16(af[mi], bfm[ni], acc[mi][ni], 0, 0, 0);
    __syncthreads();
  }

  if (MODE == 0) {
    #pragma unroll
    for (int mi = 0; mi < 4; ++mi)
      #pragma unroll
      for (int r = 0; r < 4; ++r) {
        const int row = m0 + wm + mi * 16 + lg * 4 + r;
        float* orow = outf + (int64_t)row * N + n0 + wn + lr;
        #pragma unroll
        for (int ni = 0; ni < 4; ++ni) orow[ni * 16] = acc[mi][ni][r];
      }
  } else {
    #pragma unroll
    for (int mi = 0; mi < 4; ++mi) {
      #pragma unroll
      for (int r = 0; r < 4; ++r) {
        const int row = m0 + wm + mi * 16 + lg * 4 + r;
        const int bb = row >> 11, ss = row & 2047;
        #pragma unroll
        for (int ni = 0; ni < 4; ++ni) {
          const int n = n0 + wn + ni * 16 + lr;
          float v = acc[mi][ni][r];
          if (n < 2048) {                       // Q or K: RoPE (wave-uniform branch)
            float partner = __shfl_xor(v, 1);
            const int ii = (n >> 1) & 31;
            const float c = cosT[ss * 32 + ii];
            const float sn = sinT[ss * 32 + ii];
            float rv = (n & 1) ? (partner * sn + v * c) : (v * c - partner * sn);
            const int h = (n >> 6) & 15, d = n & 63;
            const int idx = ((bb * 16 + h) * 2048 + ss) * 64 + d;
            // Q: fold 1/sqrt(D)=1/32 AND log2(e) so softmax runs in exp2 domain
            if (n < 1024) Qb[idx] = f2bf(rv * 0.0450842298f);
            else          Kb[idx] = f2bf(rv);
          } else {                              // V: store transposed [bh][d][s]
            const int n2 = n - 2048;
            const int h = n2 >> 6, d = n2 & 63;
            VbT[((int64_t)(bb * 16 + h) * 64 + d) * 2048 + ss] = f2bf(v);
          }
        }
      }
    }
  }
}

// ---------- 3: flash attention ----------
// grid: 512 = 32 (b*h) * 16 qblocks; block: 4 waves, each owns 32 q-rows.
// KVBLK=64. swapped QK^T: S^T = mfma32x32x16(K, Q) -> lane owns query ql,
// 32 of 64 key-scores in-lane (hi split with lane^32 partner).
// P fragments built fully in-register via v_cvt_pk_bf16_f32 + v_permlane32_swap.
__global__ __launch_bounds__(256, 2)
void attn_kernel(const u16* __restrict__ Qb, const u16* __restrict__ Kb,
                 const u16* __restrict__ VbT, u16* __restrict__ attnb,
                 const int* __restrict__ lens) {
  __shared__ alignas(16) u16 Klds[2][64 * 64];   // [key][d], 128B rows, slot^=(row&7)
  __shared__ alignas(16) u16 Vlds[2][64 * 64];   // [d][key], 128B rows, slot^=(row&7)
  const int tid = threadIdx.x, lane = tid & 63, wid = tid >> 6;
  const int hi = lane >> 5, ql = lane & 31;
  const int bh = blockIdx.x >> 4;
  const int len = lens[bh >> 4];
  const int qrow = (blockIdx.x & 15) * 128 + wid * 32 + ql;

  // Q fragments (loop-invariant): B-operand, chunk c: d = c*16 + hi*8 + j
  bf16x8 qf[4];
  const u16* qptr = Qb + ((int64_t)bh * 2048 + qrow) * 64 + hi * 8;
  #pragma unroll
  for (int c = 0; c < 4; ++c) qf[c] = *(const bf16x8*)(qptr + c * 16);

  // staging: pre-swizzled global source, linear LDS dest (G21)
  const int srow = tid >> 3, schunk = (tid & 7) ^ (srow & 7);
  const u16* kg = Kb + ((int64_t)bh * 2048 + srow) * 64 + schunk * 8;
  const u16* vg = VbT + ((int64_t)bh * 64 + srow) * 2048 + schunk * 8;
  const int dstoff = wid * 512;                  // u16; HW adds lane*16B

  f32x16 oacc[2];
  #pragma unroll
  for (int r = 0; r < 16; ++r) { oacc[0][r] = 0.0f; oacc[1][r] = 0.0f; }
  float mrun = -1e30f, lrun = 0.0f;

  const int nt = (len + 63) >> 6;
  gload_lds16(kg,             &Klds[0][dstoff]);
  gload_lds16(kg + 32 * 64,   &Klds[0][2048 + dstoff]);
  gload_lds16(vg,             &Vlds[0][dstoff]);
  gload_lds16(vg + 32 * 2048, &Vlds[0][2048 + dstoff]);
  __syncthreads();

  const u16* kgn = kg + 64 * 64;   // next-tile pointers
  const u16* vgn = vg + 64;

  for (int t = 0; t < nt; ++t) {
    const int bu = t & 1;
    if (t + 1 < nt) {                       // prefetch next tile into other buffer
      gload_lds16(kgn,             &Klds[bu ^ 1][dstoff]);
      gload_lds16(kgn + 32 * 64,   &Klds[bu ^ 1][2048 + dstoff]);
      gload_lds16(vgn,             &Vlds[bu ^ 1][dstoff]);
      gload_lds16(vgn + 32 * 2048, &Vlds[bu ^ 1][2048 + dstoff]);
    }
    kgn += 64 * 64; vgn += 64;

    // QK^T: A = K rows (key = kh*32 + ql), B = Q frags
    f32x16 s0, s1;
    #pragma unroll
    for (int r = 0; r < 16; ++r) { s0[r] = 0.0f; s1[r] = 0.0f; }
    __builtin_amdgcn_s_setprio(1);
    #pragma unroll
    for (int c = 0; c < 4; ++c) {
      const int slot = (((2 * c + hi) ^ (ql & 7)) * 8);
      bf16x8 kf0 = *(const bf16x8*)&Klds[bu][ql * 64 + slot];
      bf16x8 kf1 = *(const bf16x8*)&Klds[bu][(32 + ql) * 64 + slot];
      s0 = __builtin_amdgcn_mfma_f32_32x32x16_bf16(kf0, qf[c], s0, 0, 0, 0);
      s1 = __builtin_amdgcn_mfma_f32_32x32x16_bf16(kf1, qf[c], s1, 0, 0, 0);
    }
    __builtin_amdgcn_s_setprio(0);

    const int k0 = t * 64;
    if (k0 + 64 > len) {                    // mask padded keys (last tile only)
      #pragma unroll
      for (int r = 0; r < 16; ++r) {
        const int key = k0 + (r & 3) + 8 * (r >> 2) + 4 * hi;
        if (key >= len) s0[r] = -1e30f;
        if (key + 32 >= len) s1[r] = -1e30f;
      }
    }

    // online softmax (exp2 domain; log2e folded into Q)
    float ma = fmaxf(s0[0], s1[0]), mb = fmaxf(s0[1], s1[1]);
    float mc = fmaxf(s0[2], s1[2]), md = fmaxf(s0[3], s1[3]);
    #pragma unroll
    for (int r = 4; r < 16; r += 4) {
      ma = fmaxf(ma, fmaxf(s0[r], s1[r]));
      mb = fmaxf(mb, fmaxf(s0[r + 1], s1[r + 1]));
      mc = fmaxf(mc, fmaxf(s0[r + 2], s1[r + 2]));
      md = fmaxf(md, fmaxf(s0[r + 3], s1[r + 3]));
    }
    float mx = fmaxf(fmaxf(ma, mb), fmaxf(mc, md));
    mx = fmaxf(mx, __shfl_xor(mx, 32));
    if (!__all(mx - mrun <= 11.0f)) {       // defer-max (T13): rescale only on real growth
      const float mnew = fmaxf(mrun, mx);
      const float sc = exp2_fast(mrun - mnew);
      #pragma unroll
      for (int r = 0; r < 16; ++r) { oacc[0][r] *= sc; oacc[1][r] *= sc; }
      lrun *= sc;
      mrun = mnew;
    }
    float p[32];
    float ps0 = 0.0f, ps1 = 0.0f, ps2 = 0.0f, ps3 = 0.0f;
    #pragma unroll
    for (int r = 0; r < 16; r += 4) {
      p[r]      = exp2_fast(s0[r] - mrun);
      p[r + 1]  = exp2_fast(s0[r + 1] - mrun);
      p[r + 2]  = exp2_fast(s0[r + 2] - mrun);
      p[r + 3]  = exp2_fast(s0[r + 3] - mrun);
      p[16 + r]     = exp2_fast(s1[r] - mrun);
      p[16 + r + 1] = exp2_fast(s1[r + 1] - mrun);
      p[16 + r + 2] = exp2_fast(s1[r + 2] - mrun);
      p[16 + r + 3] = exp2_fast(s1[r + 3] - mrun);
      ps0 += p[r] + p[16 + r];
      ps1 += p[r + 1] + p[16 + r + 1];
      ps2 += p[r + 2] + p[16 + r + 2];
      ps3 += p[r + 3] + p[16 + r + 3];
    }
    float psum = (ps0 + ps1) + (ps2 + ps3);
    psum += __shfl_xor(psum, 32);
    lrun += psum;

    // P -> bf16 MFMA B-fragments fully in-register (T12)
    bf16x8 pfrag[4];
    #pragma unroll
    for (int ks = 0; ks < 4; ++ks) {
      uint32_t a0, a1, a2, a3;
      CVTPK(a0, p[8 * ks + 0], p[8 * ks + 1]);
      CVTPK(a1, p[8 * ks + 2], p[8 * ks + 3]);
      CVTPK(a2, p[8 * ks + 4], p[8 * ks + 5]);
      CVTPK(a3, p[8 * ks + 6], p[8 * ks + 7]);
      SWAP32(a0, a2);
      SWAP32(a1, a3);
      union { uint32_t u[4]; bf16x8 v; } pw;
      pw.u[0] = a0; pw.u[1] = a1; pw.u[2] = a2; pw.u[3] = a3;
      pfrag[ks] = pw.v;
    }

    // PV: O^T += V^T * P   (A = V^T rows d = dc*32 + ql)
    __builtin_amdgcn_s_setprio(1);
    #pragma unroll
    for (int dc = 0; dc < 2; ++dc) {
      const int drow = dc * 32 + ql;
      #pragma unroll
      for (int ks = 0; ks < 4; ++ks) {
        const int slot = (((2 * ks + hi) ^ (ql & 7)) * 8);
        bf16x8 vf = *(const bf16x8*)&Vlds[bu][drow * 64 + slot];
        oacc[dc] = __builtin_amdgcn_mfma_f32_32x32x16_bf16(vf, pfrag[ks], oacc[dc], 0, 0, 0);
      }
    }
    __builtin_amdgcn_s_setprio(0);
    __syncthreads();
  }

  // epilogue: normalize, write attn[row][h*64+d] as bf16
  const float inv = 1.0f / lrun;
  u16* outp = attnb + ((int64_t)((bh >> 4) * 2048 + qrow)) * 1024 + (bh & 15) * 64;
  #pragma unroll
  for (int dc = 0; dc < 2; ++dc)
    #pragma unroll
    for (int g = 0; g < 4; ++g) {
      ushort4 w;
      w.x = f2bf(oacc[dc][4 * g + 0] * inv);
      w.y = f2bf(oacc[dc][4 * g + 1] * inv);
      w.z = f2bf(oacc[dc][4 * g + 2] * inv);
      w.w = f2bf(oacc[dc][4 * g + 3] * inv);
      *(ushort4*)(outp + dc * 32 + 8 * g + 4 * hi) = w;
    }
}

// ---------- launch ----------
extern "C" void kernel_launch(void* const* d_in, const int* in_sizes, int n_in,
                              void* d_out, int out_size, void* d_ws, size_t ws_size,
                              hipStream_t stream) {
  const float* x    = (const float*)d_in[0];
  const float* wq   = (const float*)d_in[1];
  const float* wk   = (const float*)d_in[2];
  const float* wv   = (const float*)d_in[3];
  const float* wo   = (const float*)d_in[4];
  const float* fcos = (const float*)d_in[5];
  const float* fsin = (const float*)d_in[6];
  const int*   pmsk = (const int*)d_in[7];
  float* out = (float*)d_out;

  char* ws = (char*)d_ws;
  u16* XB    = (u16*)(ws);                          // 8 MB
  u16* WQKV  = (u16*)(ws + (size_t)8  * 1048576);   // 6 MB
  u16* WOB   = (u16*)(ws + (size_t)14 * 1048576);   // 2 MB
  u16* QB    = (u16*)(ws + (size_t)16 * 1048576);   // 8 MB
  u16* KB    = (u16*)(ws + (size_t)24 * 1048576);   // 8 MB
  u16* VBT   = (u16*)(ws + (size_t)32 * 1048576);   // 8 MB
  u16* ATTNB = (u16*)(ws + (size_t)40 * 1048576);   // 8 MB
  int* LENS  = (int*)(ws + (size_t)48 * 1048576);

  cvt_kernel<<<2048, 256, 0, stream>>>((const float4*)x, (const float4*)wq,
                                       (const float4*)wk, (const float4*)wv,
                                       (const float4*)wo, (ushort4*)XB,
                                       (ushort4*)WQKV, (ushort4*)WOB);
  len_kernel<<<2, 256, 0, stream>>>(pmsk, LENS);
  gemm_bt<1><<<768, 256, 0, stream>>>(XB, WQKV, 4096, 3072, nullptr,
                                      QB, KB, VBT, fcos, fsin);
  attn_kernel<<<512, 256, 0, stream>>>(QB, KB, VBT, ATTNB, LENS);
  gemm_bt<0><<<256, 256, 0, stream>>>(ATTNB, WOB, 4096, 1024, out,
                                      nullptr, nullptr, nullptr, nullptr, nullptr);
}